// Round 11
// baseline (185.659 us; speedup 1.0000x reference)
//
#include <hip/hip_runtime.h>
#include <math.h>

#define N_REF   50000
#define BATCH   16
#define KDIM    4096          // 32*128
#define CHUNK   256           // k-chunk in floats
#define NCHUNK  (KDIM / CHUNK) // 16
#define RPB     16            // n-rows per block
#define RPW     4             // n-rows per wave (unique rows -> raw read exactly once)
#define NBLK    (N_REF / RPB) // 3125 dist blocks
#define PSTRIDE 3200          // padded partial stride per batch row

typedef float f32x4 __attribute__((ext_vector_type(4)));
typedef __attribute__((address_space(3))) uint32_t lds_u32;
typedef const __attribute__((address_space(1))) uint32_t glb_u32;

// K1: dist'[b,n] = r2[n] - 2*dot(x[b], raw[n])   (x2[b] dropped: softmax-invariant)
// + FUSED partial softmax: per-block (max, sumexp) per batch row, computed from
// values already in registers -> kills softmax_part's 3.2 MB re-read + exp pass.
//
// dist structure = R7 (183.5us best): LDS-staged x via global_load_lds, double
// buffer, 1 barrier/chunk, nontemporal raw loads (evict-first keeps x L2-hot).
// Ledger: R6 counted-vmcnt null; R8 CHUNK=512 page-contiguity -4%; R9 full
// streaming policy (sc0 nt sc1) null -> dist read stream is at its practical
// ceiling (~4.9 TB/s for this pattern); reverted to the simpler builtin.
// No min-waves launch bound: R1's (256,3) capped VGPR at 84 -> 1 GB spill.
__global__ __launch_bounds__(256) void dist_kernel(const float* __restrict__ x,
                                                   const float* __restrict__ raw,
                                                   float* __restrict__ dist,
                                                   float2* __restrict__ part)
{
    __shared__ float xs[2][BATCH * CHUNK];   // double-buffered, 2 x 16 KiB
    const int tid  = threadIdx.x;
    const int lane = tid & 63;
    const int wv   = tid >> 6;               // 0..3
    const long n_base = (long)blockIdx.x * RPB + (long)wv * RPW;

    float acc[BATCH][RPW];
    #pragma unroll
    for (int b = 0; b < BATCH; ++b)
        #pragma unroll
        for (int r = 0; r < RPW; ++r) acc[b][r] = 0.f;
    float r2a[RPW] = {0.f, 0.f, 0.f, 0.f};
    f32x4 rv[RPW];

#define STAGE(buf, c) do {                                                      \
        _Pragma("unroll")                                                       \
        for (int i_ = 0; i_ < 4; ++i_) {                                        \
            const int b_ = i_ * 4 + wv;                                         \
            const float* g_ = x + (size_t)b_ * KDIM + (size_t)(c) * CHUNK + lane * 4; \
            const float* l_ = &xs[buf][b_ * CHUNK];                             \
            __builtin_amdgcn_global_load_lds((glb_u32*)g_, (lds_u32*)l_, 16, 0, 0); \
        }                                                                       \
    } while (0)

    // nontemporal: raw is read-once; evict-first policy preserves x in L2
#define LOADRV(c) do {                                                          \
        _Pragma("unroll")                                                       \
        for (int r_ = 0; r_ < RPW; ++r_)                                        \
            rv[r_] = __builtin_nontemporal_load(                                \
                (const f32x4*)(raw + (size_t)(n_base + r_) * KDIM               \
                                   + (size_t)(c) * CHUNK + lane * 4));          \
    } while (0)

#define COMPUTE(buf) do {                                                       \
        _Pragma("unroll")                                                       \
        for (int r_ = 0; r_ < RPW; ++r_) {                                      \
            r2a[r_] = fmaf(rv[r_].x, rv[r_].x, r2a[r_]);                        \
            r2a[r_] = fmaf(rv[r_].y, rv[r_].y, r2a[r_]);                        \
            r2a[r_] = fmaf(rv[r_].z, rv[r_].z, r2a[r_]);                        \
            r2a[r_] = fmaf(rv[r_].w, rv[r_].w, r2a[r_]);                        \
        }                                                                       \
        _Pragma("unroll")                                                       \
        for (int b_ = 0; b_ < BATCH; ++b_) {                                    \
            const f32x4 xv_ = *(const f32x4*)(&xs[buf][b_ * CHUNK + lane * 4]); \
            _Pragma("unroll")                                                   \
            for (int r_ = 0; r_ < RPW; ++r_) {                                  \
                acc[b_][r_] = fmaf(rv[r_].x, xv_.x, acc[b_][r_]);               \
                acc[b_][r_] = fmaf(rv[r_].y, xv_.y, acc[b_][r_]);               \
                acc[b_][r_] = fmaf(rv[r_].z, xv_.z, acc[b_][r_]);               \
                acc[b_][r_] = fmaf(rv[r_].w, xv_.w, acc[b_][r_]);               \
            }                                                                   \
        }                                                                       \
    } while (0)

    // prologue: stage chunk 0, barrier (drains vmcnt -> buffer 0 ready)
    STAGE(0, 0);
    __syncthreads();

    int buf = 0;
    #pragma unroll 1
    for (int c = 0; c < NCHUNK - 1; ++c) {
        LOADRV(c);              // oldest: pre-FMA wait leaves stage in flight
        STAGE(buf ^ 1, c + 1);
        COMPUTE(buf);
        __syncthreads();
        buf ^= 1;
    }
    LOADRV(NCHUNK - 1);
    COMPUTE(buf);

    // Cross-lane reduce of 64 accumulators: value v = b*4+r ends (summed) on lane v.
    float vals[64];
    #pragma unroll
    for (int b = 0; b < BATCH; ++b)
        #pragma unroll
        for (int r = 0; r < RPW; ++r) vals[b * RPW + r] = acc[b][r];

    #pragma unroll
    for (int k = 0; k < 6; ++k) {
        const int bit = 1 << k;
        const bool hi = (lane & bit) != 0;
        #pragma unroll
        for (int i = 0; i < (64 >> (k + 1)); ++i) {
            const float a  = vals[2 * i];
            const float bb = vals[2 * i + 1];
            const float keep = hi ? bb : a;
            const float send = hi ? a  : bb;
            const float recv = __shfl_xor(send, bit, 64);
            vals[i] = keep + recv;
        }
    }

    // r2: broadcast-reduce the 4 row sums to all lanes
    #pragma unroll
    for (int r = 0; r < RPW; ++r) {
        #pragma unroll
        for (int k = 0; k < 6; ++k)
            r2a[r] += __shfl_xor(r2a[r], 1 << k, 64);
    }

    const int b_out = lane >> 2;
    const int r_out = lane & 3;
    const float r2v = (r_out == 0) ? r2a[0] : (r_out == 1) ? r2a[1]
                    : (r_out == 2) ? r2a[2] : r2a[3];
    const float d = r2v - 2.0f * vals[0];
    dist[(size_t)b_out * N_REF + (size_t)(n_base + r_out)] = d;

    // ---- fused partial softmax: block-local (max, sumexp) per batch row ----
    // quad reduce (lanes 4b..4b+3 hold batch b's 4 n-values):
    float m = d;
    m = fmaxf(m, __shfl_xor(m, 1, 64));
    m = fmaxf(m, __shfl_xor(m, 2, 64));
    float s = __expf(d - m);
    s += __shfl_xor(s, 1, 64);
    s += __shfl_xor(s, 2, 64);

    float2* xs_f2 = (float2*)&xs[0][0];      // reuse xs: 4 waves x 16 b x float2
    __syncthreads();                         // all waves done with xs (COMPUTE)
    if ((lane & 3) == 0) xs_f2[wv * BATCH + b_out] = make_float2(m, s);
    __syncthreads();
    if (tid < BATCH) {                       // merge 4 wave-partials for batch=tid
        float2 p0 = xs_f2[tid];
        float M = p0.x, S = p0.y;
        #pragma unroll
        for (int w = 1; w < 4; ++w) {
            const float2 pw = xs_f2[w * BATCH + tid];
            const float M2 = fmaxf(M, pw.x);
            S = S * __expf(M - M2) + pw.y * __expf(pw.x - M2);
            M = M2;
        }
        part[(size_t)tid * PSTRIDE + blockIdx.x] = make_float2(M, S);
    }
}

// K2: merge 3125 block-partials per batch row -> gms[b] = (M, 1/S). Tiny.
__global__ __launch_bounds__(256) void softmax_merge(const float2* __restrict__ part,
                                                     float2* __restrict__ gms)
{
    const int b = blockIdx.x;
    const int tid = threadIdx.x;
    float M = -INFINITY, S = 0.f;
    for (int i = tid; i < NBLK; i += 256) {
        const float2 p = part[(size_t)b * PSTRIDE + i];
        const float M2 = fmaxf(M, p.x);
        S = S * __expf(M - M2) + p.y * __expf(p.x - M2);
        M = M2;
    }
    #pragma unroll
    for (int k = 1; k < 64; k <<= 1) {
        const float mo = __shfl_xor(M, k, 64);
        const float so = __shfl_xor(S, k, 64);
        const float M2 = fmaxf(M, mo);
        S = S * __expf(M - M2) + so * __expf(mo - M2);
        M = M2;
    }
    __shared__ float2 wsum[4];
    const int wv = tid >> 6, lane = tid & 63;
    if (lane == 0) wsum[wv] = make_float2(M, S);
    __syncthreads();
    if (tid == 0) {
        float Mf = wsum[0].x, Sf = wsum[0].y;
        #pragma unroll
        for (int i = 1; i < 4; ++i) {
            const float M2 = fmaxf(Mf, wsum[i].x);
            Sf = Sf * __expf(Mf - M2) + wsum[i].y * __expf(wsum[i].x - M2);
            Mf = M2;
        }
        gms[b] = make_float2(Mf, 1.f / Sf);
    }
}

// K3: normalize in-place using the global (M, 1/S)
#define SMB   25      // col-blocks per row
#define SMC   2000    // cols per block (= 500 float4)

__global__ __launch_bounds__(256) void softmax_norm(float* __restrict__ d,
                                                    const float2* __restrict__ gms)
{
    const int row = blockIdx.y, cb = blockIdx.x;
    const float2 ms = gms[row];
    const float M = ms.x, Sinv = ms.y;

    float* p = d + (size_t)row * N_REF + (size_t)cb * SMC;
    const int tid = threadIdx.x;
    #pragma unroll
    for (int i = 0; i < 2; ++i) {
        const int q = tid + i * 256;
        if (q < SMC / 4) {
            float4 v = *(float4*)(p + q * 4);
            v.x = __expf(v.x - M) * Sinv;
            v.y = __expf(v.y - M) * Sinv;
            v.z = __expf(v.z - M) * Sinv;
            v.w = __expf(v.w - M) * Sinv;
            *(float4*)(p + q * 4) = v;
        }
    }
}

extern "C" void kernel_launch(void* const* d_in, const int* in_sizes, int n_in,
                              void* d_out, int out_size, void* d_ws, size_t ws_size,
                              hipStream_t stream) {
    const float* x   = (const float*)d_in[0];   // [16][32][128]
    const float* raw = (const float*)d_in[1];   // [50000][32][128]
    float* out = (float*)d_out;                 // [16][50000]
    float2* part = (float2*)d_ws;               // [16][PSTRIDE] float2 partials
    float2* gms  = (float2*)((char*)d_ws + (size_t)BATCH * PSTRIDE * sizeof(float2));

    dist_kernel<<<NBLK, 256, 0, stream>>>(x, raw, out, part);
    softmax_merge<<<BATCH, 256, 0, stream>>>(part, gms);
    softmax_norm<<<dim3(SMB, BATCH), 256, 0, stream>>>(out, gms);
}

// Round 12
// 183.956 us; speedup vs baseline: 1.0093x; 1.0093x over previous
//
#include <hip/hip_runtime.h>
#include <math.h>

#define N_REF   50000
#define BATCH   16
#define KDIM    4096          // 32*128
#define CHUNK   256           // k-chunk in floats
#define NCHUNK  (KDIM / CHUNK) // 16
#define RPB     16            // n-rows per block
#define RPW     4             // n-rows per wave (unique rows -> raw read exactly once)

typedef float f32x4 __attribute__((ext_vector_type(4)));  // native vec for nontemporal builtin
typedef __attribute__((address_space(3))) uint32_t lds_u32;
typedef const __attribute__((address_space(1))) uint32_t glb_u32;

// K1: dist'[b,n] = r2[n] - 2*dot(x[b], raw[n])   (x2[b] dropped: softmax-invariant)
//
// FINAL (R7 structure, 183.5us validated): LDS-staged x via global_load_lds,
// double buffer, one __syncthreads per chunk, NONTEMPORAL raw loads (evict-
// first keeps x's 256KB L2-resident under the 819MB read-once raw stream).
// Ledger of falsified levers (all <=+-4%): R6 counted-vmcnt barrier (null),
// R8 2KB DRAM-page granule (-4%), R9 no-allocate sc0-nt-sc1 policy (null),
// R10 softmax fusion into epilogue (null), R5 no-LDS x (-84%: L1 thrash),
// R2 batch-split waves (-64%: doubled raw requests). Measured sustained
// ~4.9-5.0 TB/s pure-read across all variants = practical ceiling for this
// access shape; VALU 34% duty; no fp32 MFMA exists (and bf16 quantization
// would break the softmax tolerance).
// No min-waves launch bound: R1's (256,3) capped VGPR at 84 -> 1 GB spill.
__global__ __launch_bounds__(256) void dist_kernel(const float* __restrict__ x,
                                                   const float* __restrict__ raw,
                                                   float* __restrict__ dist)
{
    __shared__ float xs[2][BATCH * CHUNK];   // double-buffered, 2 x 16 KiB
    const int tid  = threadIdx.x;
    const int lane = tid & 63;
    const int wv   = tid >> 6;               // 0..3
    const long n_base = (long)blockIdx.x * RPB + (long)wv * RPW;

    float acc[BATCH][RPW];
    #pragma unroll
    for (int b = 0; b < BATCH; ++b)
        #pragma unroll
        for (int r = 0; r < RPW; ++r) acc[b][r] = 0.f;
    float r2a[RPW] = {0.f, 0.f, 0.f, 0.f};
    f32x4 rv[RPW];

#define STAGE(buf, c) do {                                                      \
        _Pragma("unroll")                                                       \
        for (int i_ = 0; i_ < 4; ++i_) {                                        \
            const int b_ = i_ * 4 + wv;                                         \
            const float* g_ = x + (size_t)b_ * KDIM + (size_t)(c) * CHUNK + lane * 4; \
            const float* l_ = &xs[buf][b_ * CHUNK];                             \
            __builtin_amdgcn_global_load_lds((glb_u32*)g_, (lds_u32*)l_, 16, 0, 0); \
        }                                                                       \
    } while (0)

    // nontemporal: raw is read-once; evict-first policy preserves x in L2
#define LOADRV(c) do {                                                          \
        _Pragma("unroll")                                                       \
        for (int r_ = 0; r_ < RPW; ++r_)                                        \
            rv[r_] = __builtin_nontemporal_load(                                \
                (const f32x4*)(raw + (size_t)(n_base + r_) * KDIM               \
                                   + (size_t)(c) * CHUNK + lane * 4));          \
    } while (0)

#define COMPUTE(buf) do {                                                       \
        _Pragma("unroll")                                                       \
        for (int r_ = 0; r_ < RPW; ++r_) {                                      \
            r2a[r_] = fmaf(rv[r_].x, rv[r_].x, r2a[r_]);                        \
            r2a[r_] = fmaf(rv[r_].y, rv[r_].y, r2a[r_]);                        \
            r2a[r_] = fmaf(rv[r_].z, rv[r_].z, r2a[r_]);                        \
            r2a[r_] = fmaf(rv[r_].w, rv[r_].w, r2a[r_]);                        \
        }                                                                       \
        _Pragma("unroll")                                                       \
        for (int b_ = 0; b_ < BATCH; ++b_) {                                    \
            const f32x4 xv_ = *(const f32x4*)(&xs[buf][b_ * CHUNK + lane * 4]); \
            _Pragma("unroll")                                                   \
            for (int r_ = 0; r_ < RPW; ++r_) {                                  \
                acc[b_][r_] = fmaf(rv[r_].x, xv_.x, acc[b_][r_]);               \
                acc[b_][r_] = fmaf(rv[r_].y, xv_.y, acc[b_][r_]);               \
                acc[b_][r_] = fmaf(rv[r_].z, xv_.z, acc[b_][r_]);               \
                acc[b_][r_] = fmaf(rv[r_].w, xv_.w, acc[b_][r_]);               \
            }                                                                   \
        }                                                                       \
    } while (0)

    // prologue: stage chunk 0, barrier (drains vmcnt -> buffer 0 ready)
    STAGE(0, 0);
    __syncthreads();

    int buf = 0;
    #pragma unroll 1
    for (int c = 0; c < NCHUNK - 1; ++c) {
        LOADRV(c);              // oldest: pre-FMA wait leaves stage in flight
        STAGE(buf ^ 1, c + 1);
        COMPUTE(buf);
        __syncthreads();
        buf ^= 1;
    }
    LOADRV(NCHUNK - 1);
    COMPUTE(buf);

    // Cross-lane reduce of 64 accumulators: value v = b*4+r ends (summed) on lane v.
    float vals[64];
    #pragma unroll
    for (int b = 0; b < BATCH; ++b)
        #pragma unroll
        for (int r = 0; r < RPW; ++r) vals[b * RPW + r] = acc[b][r];

    #pragma unroll
    for (int k = 0; k < 6; ++k) {
        const int bit = 1 << k;
        const bool hi = (lane & bit) != 0;
        #pragma unroll
        for (int i = 0; i < (64 >> (k + 1)); ++i) {
            const float a  = vals[2 * i];
            const float bb = vals[2 * i + 1];
            const float keep = hi ? bb : a;
            const float send = hi ? a  : bb;
            const float recv = __shfl_xor(send, bit, 64);
            vals[i] = keep + recv;
        }
    }

    // r2: broadcast-reduce the 4 row sums to all lanes
    #pragma unroll
    for (int r = 0; r < RPW; ++r) {
        #pragma unroll
        for (int k = 0; k < 6; ++k)
            r2a[r] += __shfl_xor(r2a[r], 1 << k, 64);
    }

    const int b_out = lane >> 2;
    const int r_out = lane & 3;
    const float r2v = (r_out == 0) ? r2a[0] : (r_out == 1) ? r2a[1]
                    : (r_out == 2) ? r2a[2] : r2a[3];
    dist[(size_t)b_out * N_REF + (size_t)(n_base + r_out)] = r2v - 2.0f * vals[0];
}

// ---------------- softmax: two-stage, full-device ----------------
#define SMB   25      // col-blocks per row
#define SMC   2000    // cols per block (= 500 float4)

__global__ __launch_bounds__(256) void softmax_part(const float* __restrict__ d,
                                                    float2* __restrict__ part)
{
    const int row = blockIdx.y, cb = blockIdx.x;
    const float* p = d + (size_t)row * N_REF + (size_t)cb * SMC;
    const int tid = threadIdx.x;

    float m = -INFINITY, s = 0.f;
    #pragma unroll
    for (int i = 0; i < 2; ++i) {
        const int q = tid + i * 256;          // float4 index within block
        if (q < SMC / 4) {
            const float4 v = *(const float4*)(p + q * 4);
            const float M = fmaxf(m, fmaxf(fmaxf(v.x, v.y), fmaxf(v.z, v.w)));
            s = s * __expf(m - M) + __expf(v.x - M) + __expf(v.y - M)
                                  + __expf(v.z - M) + __expf(v.w - M);
            m = M;
        }
    }
    #pragma unroll
    for (int k = 1; k < 64; k <<= 1) {
        const float mo = __shfl_xor(m, k, 64);
        const float so = __shfl_xor(s, k, 64);
        const float M  = fmaxf(m, mo);
        s = s * __expf(m - M) + so * __expf(mo - M);
        m = M;
    }
    __shared__ float2 wsum[4];
    const int wv = tid >> 6, lane = tid & 63;
    if (lane == 0) wsum[wv] = make_float2(m, s);
    __syncthreads();
    if (tid == 0) {
        float M = wsum[0].x, S = wsum[0].y;
        #pragma unroll
        for (int i = 1; i < 4; ++i) {
            const float M2 = fmaxf(M, wsum[i].x);
            S = S * __expf(M - M2) + wsum[i].y * __expf(wsum[i].x - M2);
            M = M2;
        }
        part[row * SMB + cb] = make_float2(M, S);
    }
}

__global__ __launch_bounds__(256) void softmax_norm(float* __restrict__ d,
                                                    const float2* __restrict__ part)
{
    const int row = blockIdx.y, cb = blockIdx.x;
    const int tid = threadIdx.x;

    // every block redundantly reduces the 25 row-partials (tiny, L2-hit)
    float M = -INFINITY, S = 0.f;
    #pragma unroll
    for (int i = 0; i < SMB; ++i) {
        const float2 ps = part[row * SMB + i];
        const float M2 = fmaxf(M, ps.x);
        S = S * __expf(M - M2) + ps.y * __expf(ps.x - M2);
        M = M2;
    }
    const float Sinv = 1.f / S;

    float* p = d + (size_t)row * N_REF + (size_t)cb * SMC;
    #pragma unroll
    for (int i = 0; i < 2; ++i) {
        const int q = tid + i * 256;
        if (q < SMC / 4) {
            float4 v = *(float4*)(p + q * 4);
            v.x = __expf(v.x - M) * Sinv;
            v.y = __expf(v.y - M) * Sinv;
            v.z = __expf(v.z - M) * Sinv;
            v.w = __expf(v.w - M) * Sinv;
            *(float4*)(p + q * 4) = v;
        }
    }
}

extern "C" void kernel_launch(void* const* d_in, const int* in_sizes, int n_in,
                              void* d_out, int out_size, void* d_ws, size_t ws_size,
                              hipStream_t stream) {
    const float* x   = (const float*)d_in[0];   // [16][32][128]
    const float* raw = (const float*)d_in[1];   // [50000][32][128]
    float* out = (float*)d_out;                 // [16][50000]
    float2* part = (float2*)d_ws;               // 16*25 float2 partials

    dist_kernel<<<N_REF / RPB, 256, 0, stream>>>(x, raw, out);
    softmax_part<<<dim3(SMB, BATCH), 256, 0, stream>>>(out, part);
    softmax_norm<<<dim3(SMB, BATCH), 256, 0, stream>>>(out, part);
}